// Round 2
// baseline (1154.217 us; speedup 1.0000x reference)
//
#include <hip/hip_runtime.h>
#include <cmath>

#define EPSF 1e-15f
#define MAXN 0.99999f            // (1 - 1e-5) / sqrt(c), c=1

// ---- workspace layout (float offsets) -------------------------------------
#define OFF_ZU1  0               // 450  normalized z1 columns [75][6]
#define OFF_P1   450             // 18   zn1[6], ch1[6], sh1[6]
#define OFF_ZU2  468             // 2400 normalized z2 columns [150][16]
#define OFF_P2   2868            // 48   zn2[16], ch2[16], sh2[16]
#define OFF_PF1  2916            // 360  znf1[120], chf1[120], shf1[120]
#define OFF_PF2  3276            // 252  znf2[84]*3
#define OFF_PF3  3528            // 30   znf3[10]*3
#define OFF_BUF1 4096            // [B,6,14,14]  = 1204224
#define OFF_BUF2 (OFF_BUF1 + 1204224)   // [B,16,5,5] = 409600
#define OFF_BUF3 (OFF_BUF2 + 409600)    // [B,400]
#define OFF_BUF4 (OFF_BUF3 + 409600)    // [B,120]
#define OFF_BUF5 (OFF_BUF4 + 122880)    // [B,84]

// ---------------------------------------------------------------------------
// P0: combined weight prep. One block (64 thr) per output column across all
// five weight matrices. Butterfly reduce the column sq-norm; lane0 writes
// zn/cosh/sinh; conv layers also write the normalized column (zu).
// ---------------------------------------------------------------------------
__global__ __launch_bounds__(64) void prep_kernel(
        const float* __restrict__ z1, const float* __restrict__ r1,
        const float* __restrict__ z2, const float* __restrict__ r2,
        const float* __restrict__ zf1, const float* __restrict__ rf1,
        const float* __restrict__ zf2, const float* __restrict__ rf2,
        const float* __restrict__ zf3, const float* __restrict__ rf3,
        float* __restrict__ ws) {
    int blk = blockIdx.x, lane = threadIdx.x;
    const float* z; const float* r; int Din, Dout, o;
    float* zu = nullptr; float* par;
    if (blk < 6)        { z = z1;  r = r1;  Din = 75;  Dout = 6;   o = blk;       zu = ws + OFF_ZU1; par = ws + OFF_P1; }
    else if (blk < 22)  { z = z2;  r = r2;  Din = 150; Dout = 16;  o = blk - 6;   zu = ws + OFF_ZU2; par = ws + OFF_P2; }
    else if (blk < 142) { z = zf1; r = rf1; Din = 400; Dout = 120; o = blk - 22;  par = ws + OFF_PF1; }
    else if (blk < 226) { z = zf2; r = rf2; Din = 120; Dout = 84;  o = blk - 142; par = ws + OFF_PF2; }
    else                { z = zf3; r = rf3; Din = 84;  Dout = 10;  o = blk - 226; par = ws + OFF_PF3; }
    float s = 0.f;
    for (int f = lane; f < Din; f += 64) { float w = z[f * Dout + o]; s += w * w; }
    for (int d = 32; d; d >>= 1) s += __shfl_xor(s, d);
    float zn = fmaxf(sqrtf(s), EPSF);
    if (lane == 0) {
        par[o] = zn;
        par[Dout + o]     = coshf(2.0f * r[o]);
        par[2 * Dout + o] = sinhf(2.0f * r[o]);
    }
    if (zu)
        for (int f = lane; f < Din; f += 64) zu[f * Dout + o] = z[f * Dout + o] / zn;
}

// ---------------------------------------------------------------------------
// Shared math: expmap0(patch) -> poincare_fc -> project -> hrelu(channel).
// acc[] holds the raw-patch dot with normalized z columns on entry; on exit
// it holds the hrelu'd output. Returns its squared norm.
// ---------------------------------------------------------------------------
template<int COUT>
__device__ __forceinline__ float fc_hrelu_chain(float* acc, float n2,
        const float* __restrict__ zn, const float* __restrict__ ch,
        const float* __restrict__ sh) {
    float n = fmaxf(sqrtf(n2), EPSF);
    float t = tanhf(n);
    float s = t / n * fminf(1.0f, MAXN / fmaxf(t, EPSF));
    float cx2 = (s * s) * n2;
    float denom = fmaxf(1.0f - cx2, EPSF);
    float ys2 = 0.f;
#pragma unroll
    for (int o = 0; o < COUT; o++) {
        float arg = (2.0f * (s * acc[o]) * ch[o] - (1.0f + cx2) * sh[o]) / denom;
        float vv = 2.0f * zn[o] * asinhf(arg);
        float yy = sinhf(vv);
        acc[o] = yy; ys2 += yy * yy;
    }
    float dnm = 1.0f + sqrtf(1.0f + ys2);
    float ny2 = 0.f;
#pragma unroll
    for (int o = 0; o < COUT; o++) { acc[o] /= dnm; ny2 += acc[o] * acc[o]; }
    float ny = fmaxf(sqrtf(ny2), EPSF);
    float pf = fminf(1.0f, MAXN / ny);
    float n2b = 0.f;
#pragma unroll
    for (int o = 0; o < COUT; o++) { acc[o] *= pf; n2b += acc[o] * acc[o]; }
    float nb = fmaxf(sqrtf(n2b), EPSF);
    float fb = atanhf(fminf(nb, 1.0f - 1e-7f)) / nb;
    float m2 = 0.f;
#pragma unroll
    for (int o = 0; o < COUT; o++) { float uu = fmaxf(fb * acc[o], 0.f); acc[o] = uu; m2 += uu * uu; }
    float m = fmaxf(sqrtf(m2), EPSF);
    float tm = tanhf(m);
    float g = tm / m * fminf(1.0f, MAXN / fmaxf(tm, EPSF));
    float hn2 = 0.f;
#pragma unroll
    for (int o = 0; o < COUT; o++) { acc[o] *= g; hn2 += acc[o] * acc[o]; }
    return hn2;
}

// ---------------------------------------------------------------------------
// K1: conv1 fused logmap+conv+hrelu+pool. Block per image (1024 blocks, 256
// thr). Stage x[b] (3x32x32) in LDS, logmap in LDS, conv from LDS.
// ---------------------------------------------------------------------------
__global__ __launch_bounds__(256) void conv1_kernel(const float* __restrict__ x,
        const float* __restrict__ ws, float* __restrict__ out, float ratio) {
    __shared__ float xv[3072];
    __shared__ float zu[450];
    __shared__ float par[18];
    int b = blockIdx.x, tid = threadIdx.x;
    for (int i = tid; i < 3072; i += 256) xv[i] = x[(size_t)b * 3072 + i];
    for (int i = tid; i < 450; i += 256)  zu[i] = ws[OFF_ZU1 + i];
    if (tid < 18) par[tid] = ws[OFF_P1 + tid];
    __syncthreads();
    for (int p = tid; p < 1024; p += 256) {
        float a0 = xv[p], a1 = xv[1024 + p], a2 = xv[2048 + p];
        float n2 = a0 * a0 + a1 * a1 + a2 * a2;
        float n = fmaxf(sqrtf(n2), EPSF);
        float f = atanhf(fminf(n, 1.0f - 1e-7f)) / n * ratio;
        xv[p] = a0 * f; xv[1024 + p] = a1 * f; xv[2048 + p] = a2 * f;
    }
    __syncthreads();
    if (tid >= 196) return;
    int ph = tid / 14, pw = tid % 14;
    float best[6];
    float bestn = -1.f;
    for (int dy = 0; dy < 2; dy++) {
        for (int dx = 0; dx < 2; dx++) {
            int oy = 2 * ph + dy, ox = 2 * pw + dx;
            float acc[6] = {0.f, 0.f, 0.f, 0.f, 0.f, 0.f};
            float n2 = 0.f;
#pragma unroll
            for (int c = 0; c < 3; c++) {
#pragma unroll
                for (int i = 0; i < 5; i++) {
                    const float* row = &xv[c * 1024 + (oy + i) * 32 + ox];
                    int fb = (c * 5 + i) * 5;
#pragma unroll
                    for (int j = 0; j < 5; j++) {
                        float v = row[j];
                        n2 += v * v;
#pragma unroll
                        for (int o = 0; o < 6; o++)
                            acc[o] = fmaf(v, zu[(fb + j) * 6 + o], acc[o]);
                    }
                }
            }
            float hn2 = fc_hrelu_chain<6>(acc, n2, par, par + 6, par + 12);
            if (hn2 > bestn) {
                bestn = hn2;
#pragma unroll
                for (int o = 0; o < 6; o++) best[o] = acc[o];
            }
        }
    }
#pragma unroll
    for (int o = 0; o < 6; o++) out[(size_t)b * 1176 + o * 196 + tid] = best[o];
}

// ---------------------------------------------------------------------------
// K2: conv2 fused logmap+conv+hrelu+pool. 2 images per block (512 blocks,
// 256 thr), one thread per conv WINDOW (10x10 per image); pool via LDS argmax.
// ---------------------------------------------------------------------------
__global__ __launch_bounds__(256) void conv2_kernel(const float* __restrict__ in,
        const float* __restrict__ ws, float* __restrict__ out, float ratio) {
    __shared__ float xv[2352];
    __shared__ float zu[2400];
    __shared__ float par[48];
    __shared__ float hn2s[2][100];
    __shared__ int   wins[2][25];
    int b0 = blockIdx.x * 2, tid = threadIdx.x;
    for (int i = tid; i < 2352; i += 256) xv[i] = in[(size_t)b0 * 1176 + i];
    for (int i = tid; i < 2400; i += 256) zu[i] = ws[OFF_ZU2 + i];
    if (tid < 48) par[tid] = ws[OFF_P2 + tid];
    __syncthreads();
    for (int t = tid; t < 392; t += 256) {
        int img = t / 196, p = t % 196;
        float a[6]; float n2 = 0.f;
#pragma unroll
        for (int c = 0; c < 6; c++) { float v = xv[img * 1176 + c * 196 + p]; a[c] = v; n2 += v * v; }
        float n = fmaxf(sqrtf(n2), EPSF);
        float f = atanhf(fminf(n, 1.0f - 1e-7f)) / n * ratio;
#pragma unroll
        for (int c = 0; c < 6; c++) xv[img * 1176 + c * 196 + p] = a[c] * f;
    }
    __syncthreads();
    int img = tid >> 7, wpos = tid & 127;
    float u[16];
    if (wpos < 100) {
        int oy = wpos / 10, ox = wpos % 10;
        float acc[16];
#pragma unroll
        for (int o = 0; o < 16; o++) acc[o] = 0.f;
        float n2 = 0.f;
#pragma unroll
        for (int c = 0; c < 6; c++) {
#pragma unroll
            for (int i = 0; i < 5; i++) {
                const float* row = &xv[img * 1176 + c * 196 + (oy + i) * 14 + ox];
                int fb = (c * 5 + i) * 5;
#pragma unroll
                for (int j = 0; j < 5; j++) {
                    float v = row[j];
                    n2 += v * v;
#pragma unroll
                    for (int o = 0; o < 16; o++)
                        acc[o] = fmaf(v, zu[(fb + j) * 16 + o], acc[o]);
                }
            }
        }
        float hn2 = fc_hrelu_chain<16>(acc, n2, par, par + 16, par + 32);
#pragma unroll
        for (int o = 0; o < 16; o++) u[o] = acc[o];
        hn2s[img][wpos] = hn2;
    }
    __syncthreads();
    if (wpos < 25) {
        int ph = wpos / 5, pw = wpos % 5;
        float bv = -2.f; int bi = 0;
        for (int dy = 0; dy < 2; dy++)
            for (int dx = 0; dx < 2; dx++) {
                int w = (2 * ph + dy) * 10 + (2 * pw + dx);
                float v = hn2s[img][w];
                if (v > bv) { bv = v; bi = w; }
            }
        wins[img][wpos] = bi;
    }
    __syncthreads();
    if (wpos < 100) {
        int cell = ((wpos / 10) / 2) * 5 + (wpos % 10) / 2;
        if (wins[img][cell] == wpos) {
#pragma unroll
            for (int o = 0; o < 16; o++)
                out[(size_t)(b0 + img) * 400 + o * 25 + cell] = u[o];
        }
    }
}

// ---------------------------------------------------------------------------
// K3: hflatten fused logmap(channel)+expmap(row). Block (64 thr) per image.
// ---------------------------------------------------------------------------
__global__ __launch_bounds__(64) void flatten_kernel(const float* __restrict__ in,
        float* __restrict__ out, float ratio) {
    __shared__ float v[400];
    int b = blockIdx.x, tid = threadIdx.x;
    for (int i = tid; i < 400; i += 64) v[i] = in[(size_t)b * 400 + i];
    __syncthreads();
    if (tid < 25) {
        float a[16]; float n2 = 0.f;
#pragma unroll
        for (int c = 0; c < 16; c++) { float w = v[c * 25 + tid]; a[c] = w; n2 += w * w; }
        float n = fmaxf(sqrtf(n2), EPSF);
        float f = atanhf(fminf(n, 1.0f - 1e-7f)) / n * ratio;
#pragma unroll
        for (int c = 0; c < 16; c++) v[c * 25 + tid] = a[c] * f;
    }
    __syncthreads();
    float s = 0.f;
    for (int i = tid; i < 400; i += 64) { float w = v[i]; s += w * w; }
    for (int d = 32; d; d >>= 1) s += __shfl_xor(s, d);
    float n = fmaxf(sqrtf(s), EPSF);
    float t = tanhf(n);
    float g = t / n * fminf(1.0f, MAXN / fmaxf(t, EPSF));
    for (int i = tid; i < 400; i += 64) out[(size_t)b * 400 + i] = g * v[i];
}

// ---------------------------------------------------------------------------
// K4: poincare_fc (+ optional hrelu over output dim). Block (128) per row.
// ---------------------------------------------------------------------------
template<int DIN, int DOUT, bool RELU>
__global__ __launch_bounds__(128) void fc_kernel(const float* __restrict__ x,
        const float* __restrict__ z, const float* __restrict__ par,
        float* __restrict__ out) {
    int b = blockIdx.x, tid = threadIdx.x;
    __shared__ float xs[DIN];
    __shared__ float red[128];
    const float* zn = par; const float* ch = par + DOUT; const float* sh = par + 2 * DOUT;

    float p = 0.f;
    for (int j = tid; j < DIN; j += 128) {
        float v = x[(size_t)b * DIN + j];
        xs[j] = v;
        p += v * v;
    }
    red[tid] = p;
    __syncthreads();
    for (int s = 64; s > 0; s >>= 1) { if (tid < s) red[tid] += red[tid + s]; __syncthreads(); }
    float cx2 = red[0];
    __syncthreads();
    float denom = fmaxf(1.0f - cx2, EPSF);

    float yv = 0.f;
    if (tid < DOUT) {
        float dot = 0.f;
        for (int f = 0; f < DIN; f++) dot = fmaf(xs[f], z[f * DOUT + tid], dot);
        dot /= zn[tid];
        float arg = (2.0f * dot * ch[tid] - (1.0f + cx2) * sh[tid]) / denom;
        float vv = 2.0f * zn[tid] * asinhf(arg);
        yv = sinhf(vv);
    }
    red[tid] = (tid < DOUT) ? yv * yv : 0.f;
    __syncthreads();
    for (int s = 64; s > 0; s >>= 1) { if (tid < s) red[tid] += red[tid + s]; __syncthreads(); }
    float ys2 = red[0];
    __syncthreads();
    yv = yv / (1.0f + sqrtf(1.0f + ys2));

    red[tid] = (tid < DOUT) ? yv * yv : 0.f;
    __syncthreads();
    for (int s = 64; s > 0; s >>= 1) { if (tid < s) red[tid] += red[tid + s]; __syncthreads(); }
    float ny = fmaxf(sqrtf(red[0]), EPSF);
    __syncthreads();
    yv *= fminf(1.0f, MAXN / ny);

    if (RELU) {
        red[tid] = (tid < DOUT) ? yv * yv : 0.f;
        __syncthreads();
        for (int s = 64; s > 0; s >>= 1) { if (tid < s) red[tid] += red[tid + s]; __syncthreads(); }
        float n = fmaxf(sqrtf(red[0]), EPSF);
        __syncthreads();
        float sn = fminf(n, 1.0f - 1e-7f);
        float fb = atanhf(sn) / n;
        float u = fmaxf(fb * yv, 0.f);
        red[tid] = (tid < DOUT) ? u * u : 0.f;
        __syncthreads();
        for (int s = 64; s > 0; s >>= 1) { if (tid < s) red[tid] += red[tid + s]; __syncthreads(); }
        float m = fmaxf(sqrtf(red[0]), EPSF);
        __syncthreads();
        float tm = tanhf(m);
        float g = tm / m * fminf(1.0f, MAXN / fmaxf(tm, EPSF));
        yv = g * u;
    }
    if (tid < DOUT) out[(size_t)b * DOUT + tid] = yv;
}

// ---------------------------------------------------------------------------
static double beta_fn(double n) {
    return exp(lgamma(n / 2.0) + lgamma(0.5) - lgamma((n + 1) / 2.0));
}

extern "C" void kernel_launch(void* const* d_in, const int* in_sizes, int n_in,
                              void* d_out, int out_size, void* d_ws, size_t ws_size,
                              hipStream_t stream) {
    (void)in_sizes; (void)n_in; (void)out_size; (void)ws_size;
    const float* x   = (const float*)d_in[0];
    const float* z1  = (const float*)d_in[1];
    const float* b1  = (const float*)d_in[2];
    const float* z2  = (const float*)d_in[3];
    const float* b2  = (const float*)d_in[4];
    const float* zf1 = (const float*)d_in[5];
    const float* bf1 = (const float*)d_in[6];
    const float* zf2 = (const float*)d_in[7];
    const float* bf2 = (const float*)d_in[8];
    const float* zf3 = (const float*)d_in[9];
    const float* bf3 = (const float*)d_in[10];
    float* out = (float*)d_out;
    float* ws  = (float*)d_ws;

    const int B = 1024;
    const float ratio1 = (float)(beta_fn(75.0)  / beta_fn(3.0));
    const float ratio2 = (float)(beta_fn(150.0) / beta_fn(6.0));
    const float ratio3 = (float)(beta_fn(400.0) / beta_fn(16.0));

    float* buf1 = ws + OFF_BUF1;
    float* buf2 = ws + OFF_BUF2;
    float* buf3 = ws + OFF_BUF3;
    float* buf4 = ws + OFF_BUF4;
    float* buf5 = ws + OFF_BUF5;

    prep_kernel<<<236, 64, 0, stream>>>(z1, b1, z2, b2, zf1, bf1, zf2, bf2, zf3, bf3, ws);
    conv1_kernel<<<B, 256, 0, stream>>>(x, ws, buf1, ratio1);
    conv2_kernel<<<B / 2, 256, 0, stream>>>(buf1, ws, buf2, ratio2);
    flatten_kernel<<<B, 64, 0, stream>>>(buf2, buf3, ratio3);
    fc_kernel<400, 120, true ><<<B, 128, 0, stream>>>(buf3, zf1, ws + OFF_PF1, buf4);
    fc_kernel<120, 84,  true ><<<B, 128, 0, stream>>>(buf4, zf2, ws + OFF_PF2, buf5);
    fc_kernel<84,  10,  false><<<B, 128, 0, stream>>>(buf5, zf3, ws + OFF_PF3, out);
}

// Round 3
// 641.381 us; speedup vs baseline: 1.7996x; 1.7996x over previous
//
#include <hip/hip_runtime.h>
#include <cmath>

#define EPSF 1e-15f
#define MAXN 0.99999f            // (1 - 1e-5) / sqrt(c), c=1

// ---- workspace layout (float offsets) -------------------------------------
#define OFF_ZU1  0               // 450  normalized z1 columns [75][6]
#define OFF_P1   512             // 18   zn1[6], ch1[6], sh1[6]
#define OFF_ZU2  576             // 2400 normalized z2 columns [150][16]
#define OFF_P2   3072            // 48   zn2[16], ch2[16], sh2[16]
#define OFF_PF1  3200            // 360  znf1[120]*3
#define OFF_PF2  3584            // 252  znf2[84]*3
#define OFF_PF3  3904            // 30   znf3[10]*3
#define OFF_BUF1 4096            // [B,6,196]  = 1204224
#define OFF_BUF3 (OFF_BUF1 + 1204224)   // [B,400] = 409600

__device__ __forceinline__ float wave_reduce_sum(float s) {
#pragma unroll
    for (int d = 1; d < 64; d <<= 1) s += __shfl_xor(s, d);
    return s;
}

// ---------------------------------------------------------------------------
// P0: combined weight prep. One block (64 thr) per output column.
// ---------------------------------------------------------------------------
__global__ __launch_bounds__(64) void prep_kernel(
        const float* __restrict__ z1, const float* __restrict__ r1,
        const float* __restrict__ z2, const float* __restrict__ r2,
        const float* __restrict__ zf1, const float* __restrict__ rf1,
        const float* __restrict__ zf2, const float* __restrict__ rf2,
        const float* __restrict__ zf3, const float* __restrict__ rf3,
        float* __restrict__ ws) {
    int blk = blockIdx.x, lane = threadIdx.x;
    const float* z; const float* r; int Din, Dout, o;
    float* zu = nullptr; float* par;
    if (blk < 6)        { z = z1;  r = r1;  Din = 75;  Dout = 6;   o = blk;       zu = ws + OFF_ZU1; par = ws + OFF_P1; }
    else if (blk < 22)  { z = z2;  r = r2;  Din = 150; Dout = 16;  o = blk - 6;   zu = ws + OFF_ZU2; par = ws + OFF_P2; }
    else if (blk < 142) { z = zf1; r = rf1; Din = 400; Dout = 120; o = blk - 22;  par = ws + OFF_PF1; }
    else if (blk < 226) { z = zf2; r = rf2; Din = 120; Dout = 84;  o = blk - 142; par = ws + OFF_PF2; }
    else                { z = zf3; r = rf3; Din = 84;  Dout = 10;  o = blk - 226; par = ws + OFF_PF3; }
    float s = 0.f;
    for (int f = lane; f < Din; f += 64) { float w = z[f * Dout + o]; s += w * w; }
    s = wave_reduce_sum(s);
    float zn = fmaxf(sqrtf(s), EPSF);
    if (lane == 0) {
        par[o] = zn;
        par[Dout + o]     = coshf(2.0f * r[o]);
        par[2 * Dout + o] = sinhf(2.0f * r[o]);
    }
    if (zu)
        for (int f = lane; f < Din; f += 64) zu[f * Dout + o] = z[f * Dout + o] / zn;
}

// ---------------------------------------------------------------------------
// chain: expmap0(patch) -> poincare_fc -> project -> hrelu(channel), all
// channels in-thread. Only 2 true reductions (ys2, m2); the rest is scalar
// algebra (ny2 = ys2/dnm^2, n2b = pf^2*ny2, hn2 = g^2*m2).
// ---------------------------------------------------------------------------
template<int N>
__device__ __forceinline__ float chain_full(float* acc, float n2,
        const float* __restrict__ zn, const float* __restrict__ ch,
        const float* __restrict__ sh) {
    float n = fmaxf(sqrtf(n2), EPSF);
    float t = tanhf(n);
    float s = t / n * fminf(1.0f, MAXN / fmaxf(t, EPSF));
    float cx2 = (s * s) * n2;
    float denom = fmaxf(1.0f - cx2, EPSF);
    float ys2 = 0.f;
#pragma unroll
    for (int o = 0; o < N; o++) {
        float arg = (2.0f * (s * acc[o]) * ch[o] - (1.0f + cx2) * sh[o]) / denom;
        float yy = sinhf(2.0f * zn[o] * asinhf(arg));
        acc[o] = yy; ys2 += yy * yy;
    }
    float dnm = 1.0f + sqrtf(1.0f + ys2);
    float ny2 = ys2 / (dnm * dnm);
    float ny = fmaxf(sqrtf(ny2), EPSF);
    float pf = fminf(1.0f, MAXN / ny);
    float sc = pf / dnm;
    float n2b = pf * pf * ny2;
    float nb = fmaxf(sqrtf(n2b), EPSF);
    float fb = atanhf(fminf(nb, 1.0f - 1e-7f)) / nb;
    float m2 = 0.f;
#pragma unroll
    for (int o = 0; o < N; o++) { float uu = fmaxf(fb * sc * acc[o], 0.f); acc[o] = uu; m2 += uu * uu; }
    float m = fmaxf(sqrtf(m2), EPSF);
    float tm = tanhf(m);
    float g = tm / m * fminf(1.0f, MAXN / fmaxf(tm, EPSF));
#pragma unroll
    for (int o = 0; o < N; o++) acc[o] *= g;
    return g * g * m2;
}

// ---------------------------------------------------------------------------
// K1: conv1 fused logmap+conv+hrelu+pool. Block per image, 256 thr.
// One thread per conv window (784), pool via LDS argmax.
// ---------------------------------------------------------------------------
__global__ __launch_bounds__(256) void conv1_kernel(const float* __restrict__ x,
        const float* __restrict__ ws, float* __restrict__ out, float ratio) {
    __shared__ float xv[3072];
    __shared__ float zu[456];
    __shared__ float par[18];
    __shared__ float us[784 * 7];      // stride 7: conflict-free writes
    __shared__ float hn2s[784];
    int b = blockIdx.x, tid = threadIdx.x;
    for (int i = tid; i < 3072; i += 256) xv[i] = x[(size_t)b * 3072 + i];
    for (int i = tid; i < 450; i += 256) zu[i] = ws[OFF_ZU1 + i];
    if (tid < 18) par[tid] = ws[OFF_P1 + tid];
    __syncthreads();
    for (int p = tid; p < 1024; p += 256) {
        float a0 = xv[p], a1 = xv[1024 + p], a2 = xv[2048 + p];
        float n2 = a0 * a0 + a1 * a1 + a2 * a2;
        float n = fmaxf(sqrtf(n2), EPSF);
        float f = atanhf(fminf(n, 1.0f - 1e-7f)) / n * ratio;
        xv[p] = a0 * f; xv[1024 + p] = a1 * f; xv[2048 + p] = a2 * f;
    }
    __syncthreads();
    for (int w = tid; w < 784; w += 256) {
        int oy = w / 28, ox = w % 28;
        float acc[6] = {0.f, 0.f, 0.f, 0.f, 0.f, 0.f};
        float n2 = 0.f;
#pragma unroll
        for (int c = 0; c < 3; c++)
#pragma unroll
        for (int i = 0; i < 5; i++) {
            const float* row = &xv[c * 1024 + (oy + i) * 32 + ox];
            int fb0 = (c * 5 + i) * 5;
#pragma unroll
            for (int j = 0; j < 5; j++) {
                float v = row[j];
                n2 += v * v;
#pragma unroll
                for (int o = 0; o < 6; o++) acc[o] = fmaf(v, zu[(fb0 + j) * 6 + o], acc[o]);
            }
        }
        float hn2 = chain_full<6>(acc, n2, par, par + 6, par + 12);
#pragma unroll
        for (int o = 0; o < 6; o++) us[w * 7 + o] = acc[o];
        hn2s[w] = hn2;
    }
    __syncthreads();
    if (tid < 196) {
        int ph = tid / 14, pw = tid % 14;
        float bv = -1.f; int bw = 0;
#pragma unroll
        for (int dy = 0; dy < 2; dy++)
#pragma unroll
        for (int dx = 0; dx < 2; dx++) {
            int w = (2 * ph + dy) * 28 + (2 * pw + dx);
            float v = hn2s[w];
            if (v > bv) { bv = v; bw = w; }
        }
#pragma unroll
        for (int o = 0; o < 6; o++)
            out[(size_t)b * 1176 + o * 196 + tid] = us[bw * 7 + o];
    }
}

// ---------------------------------------------------------------------------
// K2: conv2 fused logmap+conv+hrelu+pool + hflatten. Block per image.
// Thread = (window, channel-half): 8-wide chain, pair shuffles for the two
// reductions. Pooled winners stay in LDS; flatten (logmap chan + expmap row)
// computed in-block, writes buf3 [B,400] directly.
// ---------------------------------------------------------------------------
__global__ __launch_bounds__(256) void conv2_kernel(const float* __restrict__ in,
        const float* __restrict__ ws, float* __restrict__ out,
        float ratio2, float ratio3) {
    __shared__ float xv[1176];
    __shared__ float zu[2400];
    __shared__ float par[48];
    __shared__ float us[100 * 16];
    __shared__ float hn2s[100];
    __shared__ int   win[25];
    __shared__ float fc_s[25];
    __shared__ float gs;
    int b = blockIdx.x, tid = threadIdx.x;
    for (int i = tid; i < 1176; i += 256) xv[i] = in[(size_t)b * 1176 + i];
    for (int i = tid; i < 2400; i += 256) zu[i] = ws[OFF_ZU2 + i];
    if (tid < 48) par[tid] = ws[OFF_P2 + tid];
    __syncthreads();
    if (tid < 196) {
        float a[6]; float n2 = 0.f;
#pragma unroll
        for (int c = 0; c < 6; c++) { float v = xv[c * 196 + tid]; a[c] = v; n2 += v * v; }
        float n = fmaxf(sqrtf(n2), EPSF);
        float f = atanhf(fminf(n, 1.0f - 1e-7f)) / n * ratio2;
#pragma unroll
        for (int c = 0; c < 6; c++) xv[c * 196 + tid] = a[c] * f;
    }
    __syncthreads();
    if (tid < 200) {
        int w = tid >> 1, h = tid & 1;
        int oy = w / 10, ox = w % 10;
        float acc[8];
#pragma unroll
        for (int o = 0; o < 8; o++) acc[o] = 0.f;
        float n2 = 0.f;
#pragma unroll
        for (int c = 0; c < 6; c++)
#pragma unroll
        for (int i = 0; i < 5; i++) {
            const float* row = &xv[c * 196 + (oy + i) * 14 + ox];
            const float* zr = &zu[((c * 5 + i) * 5) * 16 + 8 * h];
#pragma unroll
            for (int j = 0; j < 5; j++) {
                float v = row[j];
                n2 += v * v;
#pragma unroll
                for (int o = 0; o < 8; o++) acc[o] = fmaf(v, zr[j * 16 + o], acc[o]);
            }
        }
        const float* zn = par + 8 * h;
        const float* ch = par + 16 + 8 * h;
        const float* sh = par + 32 + 8 * h;
        float n = fmaxf(sqrtf(n2), EPSF);
        float t = tanhf(n);
        float s = t / n * fminf(1.0f, MAXN / fmaxf(t, EPSF));
        float cx2 = (s * s) * n2;
        float denom = fmaxf(1.0f - cx2, EPSF);
        float ys2h = 0.f;
#pragma unroll
        for (int o = 0; o < 8; o++) {
            float arg = (2.0f * (s * acc[o]) * ch[o] - (1.0f + cx2) * sh[o]) / denom;
            float yy = sinhf(2.0f * zn[o] * asinhf(arg));
            acc[o] = yy; ys2h += yy * yy;
        }
        float ys2 = ys2h + __shfl_xor(ys2h, 1);
        float dnm = 1.0f + sqrtf(1.0f + ys2);
        float ny2 = ys2 / (dnm * dnm);
        float ny = fmaxf(sqrtf(ny2), EPSF);
        float pf = fminf(1.0f, MAXN / ny);
        float sc = pf / dnm;
        float n2b = pf * pf * ny2;
        float nb = fmaxf(sqrtf(n2b), EPSF);
        float fb = atanhf(fminf(nb, 1.0f - 1e-7f)) / nb;
        float m2h = 0.f;
#pragma unroll
        for (int o = 0; o < 8; o++) { float uu = fmaxf(fb * sc * acc[o], 0.f); acc[o] = uu; m2h += uu * uu; }
        float m2 = m2h + __shfl_xor(m2h, 1);
        float m = fmaxf(sqrtf(m2), EPSF);
        float tm = tanhf(m);
        float g = tm / m * fminf(1.0f, MAXN / fmaxf(tm, EPSF));
#pragma unroll
        for (int o = 0; o < 8; o++) us[w * 16 + 8 * h + o] = g * acc[o];
        if (h == 0) hn2s[w] = g * g * m2;
    }
    __syncthreads();
    if (tid < 64) {
        float part = 0.f;
        if (tid < 25) {
            int ph = tid / 5, pw = tid % 5;
            float bv = -1.f; int bw = 0;
#pragma unroll
            for (int dy = 0; dy < 2; dy++)
#pragma unroll
            for (int dx = 0; dx < 2; dx++) {
                int w = (2 * ph + dy) * 10 + (2 * pw + dx);
                float v = hn2s[w];
                if (v > bv) { bv = v; bw = w; }
            }
            win[tid] = bw;
            float h2 = hn2s[bw];
            float n = fmaxf(sqrtf(h2), EPSF);
            float f = atanhf(fminf(n, 1.0f - 1e-7f)) / n * ratio3;
            fc_s[tid] = f;
            part = f * f * h2;
        }
#pragma unroll
        for (int d = 1; d < 32; d <<= 1) part += __shfl_xor(part, d);
        if (tid == 0) {
            float n = fmaxf(sqrtf(part), EPSF);
            float t = tanhf(n);
            gs = t / n * fminf(1.0f, MAXN / fmaxf(t, EPSF));
        }
    }
    __syncthreads();
    float g = gs;
    for (int i = tid; i < 400; i += 256) {
        int o = i / 25, cell = i % 25;
        out[(size_t)b * 400 + i] = g * fc_s[cell] * us[win[cell] * 16 + o];
    }
}

// ---------------------------------------------------------------------------
// K3: fused FC stack (fc1+hrelu -> fc2+hrelu -> fc3). One wave per batch row,
// up to 2 output columns per lane; wave shuffles for reductions; layer l's
// output sq-norm (g^2*m2) feeds layer l+1's cx2 directly.
// ---------------------------------------------------------------------------
template<int DIN, int DOUT, bool RELU>
__device__ __forceinline__ float fc_layer_wave(int lane, const float* __restrict__ xr,
        float cx2, const float* __restrict__ z, const float* __restrict__ par,
        float* __restrict__ dst) {
    int o0 = lane, o1 = lane + 64;
    bool v0 = o0 < DOUT, v1 = o1 < DOUT;
    int c0 = v0 ? o0 : 0, c1 = v1 ? o1 : 0;
    float d0 = 0.f, d1 = 0.f;
    for (int f = 0; f < DIN; f++) {
        float v = xr[f];
        d0 = fmaf(v, z[f * DOUT + c0], d0);
        if (DOUT > 64) d1 = fmaf(v, z[f * DOUT + c1], d1);
    }
    float denom = fmaxf(1.0f - cx2, EPSF);
    float zn0 = par[c0], ch0 = par[DOUT + c0], sh0 = par[2 * DOUT + c0];
    float arg0 = (2.0f * (d0 / zn0) * ch0 - (1.0f + cx2) * sh0) / denom;
    float y0 = sinhf(2.0f * zn0 * asinhf(arg0));
    float y1 = 0.f;
    if (DOUT > 64) {
        float zn1 = par[c1], ch1 = par[DOUT + c1], sh1 = par[2 * DOUT + c1];
        float arg1 = (2.0f * (d1 / zn1) * ch1 - (1.0f + cx2) * sh1) / denom;
        y1 = sinhf(2.0f * zn1 * asinhf(arg1));
    }
    float ys2 = wave_reduce_sum((v0 ? y0 * y0 : 0.f) + (v1 ? y1 * y1 : 0.f));
    float dnm = 1.0f + sqrtf(1.0f + ys2);
    float ny2 = ys2 / (dnm * dnm);
    float ny = fmaxf(sqrtf(ny2), EPSF);
    float pf = fminf(1.0f, MAXN / ny);
    float sc = pf / dnm;
    if (!RELU) {
        if (v0) dst[o0] = sc * y0;
        if (DOUT > 64 && v1) dst[o1] = sc * y1;
        return pf * pf * ny2;
    }
    float n2b = pf * pf * ny2;
    float nb = fmaxf(sqrtf(n2b), EPSF);
    float fb = atanhf(fminf(nb, 1.0f - 1e-7f)) / nb;
    float u0 = fmaxf(fb * sc * y0, 0.f);
    float u1 = fmaxf(fb * sc * y1, 0.f);
    float m2 = wave_reduce_sum((v0 ? u0 * u0 : 0.f) + (v1 ? u1 * u1 : 0.f));
    float m = fmaxf(sqrtf(m2), EPSF);
    float tm = tanhf(m);
    float g = tm / m * fminf(1.0f, MAXN / fmaxf(tm, EPSF));
    if (v0) dst[o0] = g * u0;
    if (DOUT > 64 && v1) dst[o1] = g * u1;
    return g * g * m2;
}

__global__ __launch_bounds__(256) void fc_stack_kernel(const float* __restrict__ in,
        const float* __restrict__ zf1, const float* __restrict__ zf2,
        const float* __restrict__ zf3, const float* __restrict__ ws,
        float* __restrict__ out) {
    __shared__ float xs[4][400];
    __shared__ float h1[4][120];
    __shared__ float h2[4][84];
    int wid = threadIdx.x >> 6, lane = threadIdx.x & 63;
    int b = blockIdx.x * 4 + wid;
    float* xr = xs[wid];
    float p = 0.f;
    for (int j = lane; j < 400; j += 64) { float v = in[(size_t)b * 400 + j]; xr[j] = v; p += v * v; }
    float cx2 = wave_reduce_sum(p);
    __syncthreads();
    float cx2b = fc_layer_wave<400, 120, true >(lane, xr,     cx2,  zf1, ws + OFF_PF1, h1[wid]);
    __syncthreads();
    float cx2c = fc_layer_wave<120, 84,  true >(lane, h1[wid], cx2b, zf2, ws + OFF_PF2, h2[wid]);
    __syncthreads();
    fc_layer_wave<84, 10, false>(lane, h2[wid], cx2c, zf3, ws + OFF_PF3, out + (size_t)b * 10);
}

// ---------------------------------------------------------------------------
static double beta_fn(double n) {
    return exp(lgamma(n / 2.0) + lgamma(0.5) - lgamma((n + 1) / 2.0));
}

extern "C" void kernel_launch(void* const* d_in, const int* in_sizes, int n_in,
                              void* d_out, int out_size, void* d_ws, size_t ws_size,
                              hipStream_t stream) {
    (void)in_sizes; (void)n_in; (void)out_size; (void)ws_size;
    const float* x   = (const float*)d_in[0];
    const float* z1  = (const float*)d_in[1];
    const float* b1  = (const float*)d_in[2];
    const float* z2  = (const float*)d_in[3];
    const float* b2  = (const float*)d_in[4];
    const float* zf1 = (const float*)d_in[5];
    const float* bf1 = (const float*)d_in[6];
    const float* zf2 = (const float*)d_in[7];
    const float* bf2 = (const float*)d_in[8];
    const float* zf3 = (const float*)d_in[9];
    const float* bf3 = (const float*)d_in[10];
    float* out = (float*)d_out;
    float* ws  = (float*)d_ws;

    const int B = 1024;
    const float ratio1 = (float)(beta_fn(75.0)  / beta_fn(3.0));
    const float ratio2 = (float)(beta_fn(150.0) / beta_fn(6.0));
    const float ratio3 = (float)(beta_fn(400.0) / beta_fn(16.0));

    float* buf1 = ws + OFF_BUF1;
    float* buf3 = ws + OFF_BUF3;

    prep_kernel<<<236, 64, 0, stream>>>(z1, b1, z2, b2, zf1, bf1, zf2, bf2, zf3, bf3, ws);
    conv1_kernel<<<B, 256, 0, stream>>>(x, ws, buf1, ratio1);
    conv2_kernel<<<B, 256, 0, stream>>>(buf1, ws, buf3, ratio2, ratio3);
    fc_stack_kernel<<<B / 4, 256, 0, stream>>>(buf3, zf1, zf2, zf3, ws, out);
}

// Round 5
// 174.764 us; speedup vs baseline: 6.6044x; 3.6700x over previous
//
#include <hip/hip_runtime.h>
#include <cmath>

#define EPSF 1e-15f
#define MAXN 0.99999f            // (1 - 1e-5) / sqrt(c), c=1

// ---- workspace layout (float offsets) -------------------------------------
#define OFF_ZU1  0               // 450  normalized z1 columns [75][6]
#define OFF_P1   512             // 18   zn1[6], ch1[6], sh1[6]
#define OFF_ZU2  576             // 2400 normalized z2 columns [150][16]
#define OFF_P2   3072            // 48   zn2[16], ch2[16], sh2[16]
#define OFF_PF1  3200            // 360  znf1[120]*3
#define OFF_PF2  3584            // 252  znf2[84]*3
#define OFF_PF3  3904            // 30   znf3[10]*3
#define OFF_BUF1 4096            // [B,6,196]  = 1204224
#define OFF_BUF3 (OFF_BUF1 + 1204224)   // [B,400] = 409600

// ---- fast transcendentals (f32, |rel err| ~ few ulp of v_exp/v_log) -------
__device__ __forceinline__ float fast_tanh_pos(float x) {   // x >= 0
    float e = __expf(-2.0f * x);
    return (1.0f - e) / (1.0f + e);
}
__device__ __forceinline__ float fast_atanh01(float x) {    // 0 <= x < 1
    return 0.5f * __logf((1.0f + x) / (1.0f - x));
}
// sinh(k * asinh(t)) = sign(t) * 0.5 * (q^k - q^-k), q = |t| + sqrt(t^2+1)
__device__ __forceinline__ float sinh_k_asinh(float t, float k) {
    float at = fabsf(t);
    float lq = __logf(at + sqrtf(fmaf(at, at, 1.0f)));
    float p = __expf(k * lq);
    float r = 0.5f * (p - 1.0f / p);
    return t < 0.f ? -r : r;
}

__device__ __forceinline__ float wave_reduce_sum(float s) {
#pragma unroll
    for (int d = 1; d < 64; d <<= 1) s += __shfl_xor(s, d);
    return s;
}

// ---------------------------------------------------------------------------
// P0: combined weight prep. One block (64 thr) per output column.
// ---------------------------------------------------------------------------
__global__ __launch_bounds__(64) void prep_kernel(
        const float* __restrict__ z1, const float* __restrict__ r1,
        const float* __restrict__ z2, const float* __restrict__ r2,
        const float* __restrict__ zf1, const float* __restrict__ rf1,
        const float* __restrict__ zf2, const float* __restrict__ rf2,
        const float* __restrict__ zf3, const float* __restrict__ rf3,
        float* __restrict__ ws) {
    int blk = blockIdx.x, lane = threadIdx.x;
    const float* z; const float* r; int Din, Dout, o;
    float* zu = nullptr; float* par;
    if (blk < 6)        { z = z1;  r = r1;  Din = 75;  Dout = 6;   o = blk;       zu = ws + OFF_ZU1; par = ws + OFF_P1; }
    else if (blk < 22)  { z = z2;  r = r2;  Din = 150; Dout = 16;  o = blk - 6;   zu = ws + OFF_ZU2; par = ws + OFF_P2; }
    else if (blk < 142) { z = zf1; r = rf1; Din = 400; Dout = 120; o = blk - 22;  par = ws + OFF_PF1; }
    else if (blk < 226) { z = zf2; r = rf2; Din = 120; Dout = 84;  o = blk - 142; par = ws + OFF_PF2; }
    else                { z = zf3; r = rf3; Din = 84;  Dout = 10;  o = blk - 226; par = ws + OFF_PF3; }
    float s = 0.f;
    for (int f = lane; f < Din; f += 64) { float w = z[f * Dout + o]; s += w * w; }
    s = wave_reduce_sum(s);
    float zn = fmaxf(sqrtf(s), EPSF);
    if (lane == 0) {
        par[o] = zn;
        par[Dout + o]     = coshf(2.0f * r[o]);
        par[2 * Dout + o] = sinhf(2.0f * r[o]);
    }
    if (zu)
        for (int f = lane; f < Din; f += 64) zu[f * Dout + o] = z[f * Dout + o] / zn;
}

// ---------------------------------------------------------------------------
// chain: expmap0(patch) -> poincare_fc -> project -> hrelu(channel), all
// in-thread. Only scalar algebra outside the two per-channel passes.
// ---------------------------------------------------------------------------
template<int N>
__device__ __forceinline__ float chain_fast(float (&a)[N], float n2,
        const float (&zn)[N], const float (&ch)[N], const float (&sh)[N]) {
    float nn = fmaxf(sqrtf(n2), EPSF);
    float t = fast_tanh_pos(nn);
    float s = t / nn * fminf(1.0f, MAXN / fmaxf(t, EPSF));
    float cx2 = (s * s) * n2;
    float denom = fmaxf(1.0f - cx2, EPSF);
    float ys2 = 0.f;
#pragma unroll
    for (int o = 0; o < N; o++) {
        float arg = (2.0f * (s * a[o]) * ch[o] - (1.0f + cx2) * sh[o]) / denom;
        float yy = sinh_k_asinh(arg, 2.0f * zn[o]);
        a[o] = yy; ys2 += yy * yy;
    }
    float dnm = 1.0f + sqrtf(1.0f + ys2);
    float ny2 = ys2 / (dnm * dnm);
    float ny = fmaxf(sqrtf(ny2), EPSF);
    float pf = fminf(1.0f, MAXN / ny);
    float sc = pf / dnm;
    float n2b = pf * pf * ny2;
    float nb = fmaxf(sqrtf(n2b), EPSF);
    float fb = fast_atanh01(fminf(nb, 1.0f - 1e-7f)) / nb;
    float m2 = 0.f;
#pragma unroll
    for (int o = 0; o < N; o++) { float uu = fmaxf(fb * sc * a[o], 0.f); a[o] = uu; m2 += uu * uu; }
    float m = fmaxf(sqrtf(m2), EPSF);
    float tm = fast_tanh_pos(m);
    float g = tm / m * fminf(1.0f, MAXN / fmaxf(tm, EPSF));
#pragma unroll
    for (int o = 0; o < N; o++) a[o] *= g;
    return g * g * m2;
}

// ---------------------------------------------------------------------------
// K1: conv1. 2 images/block, 256 thr. Thread = 7-window sliding unit
// (112 units/img). Weights read from global ws (wave-uniform -> s_load).
// ---------------------------------------------------------------------------
__global__ __launch_bounds__(256) void conv1_kernel(const float* __restrict__ x,
        const float* __restrict__ ws, float* __restrict__ out, float ratio) {
    __shared__ float xv[6144];          // 2 x [3][32][32]
    __shared__ float us[2][4704];       // [784][6]
    __shared__ float hn2s[2][784];
    int b0 = blockIdx.x * 2, tid = threadIdx.x;
    const float* zug  = ws + OFF_ZU1;
    const float* parg = ws + OFF_P1;
    for (int i = tid; i < 6144; i += 256) xv[i] = x[(size_t)b0 * 3072 + i];
    __syncthreads();
    for (int p = tid; p < 2048; p += 256) {
        int img = p >> 10, pix = p & 1023;
        float* xb = xv + img * 3072;
        float a0 = xb[pix], a1 = xb[pix + 1024], a2 = xb[pix + 2048];
        float n2 = a0 * a0 + a1 * a1 + a2 * a2;
        float nn = fmaxf(sqrtf(n2), EPSF);
        float f = fast_atanh01(fminf(nn, 1.0f - 1e-7f)) / nn * ratio;
        xb[pix] = a0 * f; xb[pix + 1024] = a1 * f; xb[pix + 2048] = a2 * f;
    }
    __syncthreads();
    if (tid < 224) {
        int img = tid / 112, u = tid % 112;
        int row = u >> 2, ox0 = (u & 3) * 7;
        const float* xb = xv + img * 3072;
        float acc[7][6];
        float n2[7];
#pragma unroll
        for (int w = 0; w < 7; w++) {
            n2[w] = 0.f;
#pragma unroll
            for (int o = 0; o < 6; o++) acc[w][o] = 0.f;
        }
#pragma unroll 1
        for (int c = 0; c < 3; c++) {
#pragma unroll 1
            for (int i = 0; i < 5; i++) {
                const float* rp = xb + c * 1024 + (row + i) * 32 + ox0;
                float xr[11];
#pragma unroll
                for (int k = 0; k < 11; k++) xr[k] = rp[k];
                const float* zp = zug + (c * 5 + i) * 30;   // wave-uniform
#pragma unroll
                for (int j = 0; j < 5; j++) {
                    float zw[6];
#pragma unroll
                    for (int o = 0; o < 6; o++) zw[o] = zp[j * 6 + o];
#pragma unroll
                    for (int w = 0; w < 7; w++) {
                        float v = xr[j + w];
                        n2[w] = fmaf(v, v, n2[w]);
#pragma unroll
                        for (int o = 0; o < 6; o++) acc[w][o] = fmaf(v, zw[o], acc[w][o]);
                    }
                }
            }
        }
        float zn[6], chv[6], shv[6];
#pragma unroll
        for (int o = 0; o < 6; o++) { zn[o] = parg[o]; chv[o] = parg[6 + o]; shv[o] = parg[12 + o]; }
#pragma unroll
        for (int w = 0; w < 7; w++) {
            float hn2 = chain_fast<6>(acc[w], n2[w], zn, chv, shv);
            int wx = row * 28 + ox0 + w;
#pragma unroll
            for (int o = 0; o < 6; o++) us[img][wx * 6 + o] = acc[w][o];
            hn2s[img][wx] = hn2;
        }
    }
    __syncthreads();
    for (int t = tid; t < 392; t += 256) {
        int img = t / 196, cell = t % 196;
        int ph = cell / 14, pw = cell % 14;
        float bv = -1.f; int bw = 0;
#pragma unroll
        for (int dy = 0; dy < 2; dy++)
#pragma unroll
        for (int dx = 0; dx < 2; dx++) {
            int w = (2 * ph + dy) * 28 + (2 * pw + dx);
            float v = hn2s[img][w];
            if (v > bv) { bv = v; bw = w; }
        }
        float* op = out + (size_t)(b0 + img) * 1176 + cell;
#pragma unroll
        for (int o = 0; o < 6; o++) op[o * 196] = us[img][bw * 6 + o];
    }
}

// ---------------------------------------------------------------------------
// K2: conv2 + hflatten. 4 images/block, 256 thr. Thread = (img, row,
// half-row of 5 windows, channel-half of 8): 40 units/img, 160 active.
// Pair reductions (other channel-half) via __shfl_xor(.,2).
// ---------------------------------------------------------------------------
__global__ __launch_bounds__(256) void conv2_kernel(const float* __restrict__ in,
        const float* __restrict__ ws, float* __restrict__ out,
        float ratio2, float ratio3) {
    __shared__ float xv[4][1176];
    __shared__ float us[4][1600];
    __shared__ float hn2s[4][100];
    __shared__ int   win[4][25];
    __shared__ float fcs[4][25];
    __shared__ float gsh[4];
    int b0 = blockIdx.x * 4, tid = threadIdx.x;
    const float* zug  = ws + OFF_ZU2;
    const float* parg = ws + OFF_P2;
    for (int i = tid; i < 4704; i += 256) xv[0][i] = in[(size_t)b0 * 1176 + i];
    __syncthreads();
    for (int t = tid; t < 784; t += 256) {
        int img = t / 196, p = t % 196;
        float* xb = xv[img];
        float a[6]; float n2 = 0.f;
#pragma unroll
        for (int c = 0; c < 6; c++) { float v = xb[c * 196 + p]; a[c] = v; n2 += v * v; }
        float nn = fmaxf(sqrtf(n2), EPSF);
        float f = fast_atanh01(fminf(nn, 1.0f - 1e-7f)) / nn * ratio2;
#pragma unroll
        for (int c = 0; c < 6; c++) xb[c * 196 + p] = a[c] * f;
    }
    __syncthreads();
    if (tid < 160) {
        int img = tid / 40, r = tid % 40;
        int row = r >> 2, q = r & 3;
        int ox0 = (q & 1) * 5, h = q >> 1;
        const float* xb = xv[img];
        float acc[5][8];
        float n2[5];
#pragma unroll
        for (int w = 0; w < 5; w++) {
            n2[w] = 0.f;
#pragma unroll
            for (int o = 0; o < 8; o++) acc[w][o] = 0.f;
        }
#pragma unroll 1
        for (int c = 0; c < 6; c++) {
#pragma unroll 1
            for (int i = 0; i < 5; i++) {
                const float* rp = xb + c * 196 + (row + i) * 14 + ox0;
                float xr[9];
#pragma unroll
                for (int k = 0; k < 9; k++) xr[k] = rp[k];
                const float* zp = zug + (c * 5 + i) * 80 + 8 * h;
#pragma unroll
                for (int j = 0; j < 5; j++) {
                    float zw[8];
#pragma unroll
                    for (int o = 0; o < 8; o++) zw[o] = zp[j * 16 + o];
#pragma unroll
                    for (int w = 0; w < 5; w++) {
                        float v = xr[j + w];
                        n2[w] = fmaf(v, v, n2[w]);
#pragma unroll
                        for (int o = 0; o < 8; o++) acc[w][o] = fmaf(v, zw[o], acc[w][o]);
                    }
                }
            }
        }
        float zn[8], chv[8], shv[8];
#pragma unroll
        for (int o = 0; o < 8; o++) {
            zn[o] = parg[8 * h + o];
            chv[o] = parg[16 + 8 * h + o];
            shv[o] = parg[32 + 8 * h + o];
        }
#pragma unroll
        for (int w = 0; w < 5; w++) {
            float nn = fmaxf(sqrtf(n2[w]), EPSF);
            float t = fast_tanh_pos(nn);
            float s = t / nn * fminf(1.0f, MAXN / fmaxf(t, EPSF));
            float cx2 = (s * s) * n2[w];
            float denom = fmaxf(1.0f - cx2, EPSF);
            float y[8];
            float ys2h = 0.f;
#pragma unroll
            for (int o = 0; o < 8; o++) {
                float arg = (2.0f * (s * acc[w][o]) * chv[o] - (1.0f + cx2) * shv[o]) / denom;
                float yy = sinh_k_asinh(arg, 2.0f * zn[o]);
                y[o] = yy; ys2h += yy * yy;
            }
            float ys2 = ys2h + __shfl_xor(ys2h, 2);   // partner: other chan-half
            float dnm = 1.0f + sqrtf(1.0f + ys2);
            float ny2 = ys2 / (dnm * dnm);
            float ny = fmaxf(sqrtf(ny2), EPSF);
            float pf = fminf(1.0f, MAXN / ny);
            float sc = pf / dnm;
            float n2b = pf * pf * ny2;
            float nb = fmaxf(sqrtf(n2b), EPSF);
            float fb = fast_atanh01(fminf(nb, 1.0f - 1e-7f)) / nb;
            float m2h = 0.f;
#pragma unroll
            for (int o = 0; o < 8; o++) { float uu = fmaxf(fb * sc * y[o], 0.f); y[o] = uu; m2h += uu * uu; }
            float m2 = m2h + __shfl_xor(m2h, 2);
            float m = fmaxf(sqrtf(m2), EPSF);
            float tm = fast_tanh_pos(m);
            float g = tm / m * fminf(1.0f, MAXN / fmaxf(tm, EPSF));
            int wx = row * 10 + ox0 + w;
#pragma unroll
            for (int o = 0; o < 8; o++) us[img][wx * 16 + 8 * h + o] = g * y[o];
            if (h == 0) hn2s[img][wx] = g * g * m2;
        }
    }
    __syncthreads();
    {
        int img = tid >> 6, l = tid & 63;
        float part = 0.f;
        if (l < 25) {
            int ph = l / 5, pw = l % 5;
            float bv = -1.f; int bw = 0;
#pragma unroll
            for (int dy = 0; dy < 2; dy++)
#pragma unroll
            for (int dx = 0; dx < 2; dx++) {
                int w = (2 * ph + dy) * 10 + (2 * pw + dx);
                float v = hn2s[img][w];
                if (v > bv) { bv = v; bw = w; }
            }
            win[img][l] = bw;
            float h2 = hn2s[img][bw];
            float nn = fmaxf(sqrtf(h2), EPSF);
            float f = fast_atanh01(fminf(nn, 1.0f - 1e-7f)) / nn * ratio3;
            fcs[img][l] = f;
            part = f * f * h2;
        }
#pragma unroll
        for (int d = 1; d < 32; d <<= 1) part += __shfl_xor(part, d);
        if (l == 0) {
            float nn = fmaxf(sqrtf(part), EPSF);
            float t = fast_tanh_pos(nn);
            gsh[img] = t / nn * fminf(1.0f, MAXN / fmaxf(t, EPSF));
        }
    }
    __syncthreads();
    for (int i = tid; i < 1600; i += 256) {
        int img = i / 400, k = i % 400, o = k / 25, cell = k % 25;
        out[(size_t)(b0 + img) * 400 + k] =
            gsh[img] * fcs[img][cell] * us[img][win[img][cell] * 16 + o];
    }
}

// ---------------------------------------------------------------------------
// K3: fused FC stack. One wave per batch row; layer l's output sq-norm
// feeds layer l+1's cx2 directly.
// ---------------------------------------------------------------------------
template<int DIN, int DOUT, bool RELU>
__device__ __forceinline__ float fc_layer_wave(int lane, const float* __restrict__ xr,
        float cx2, const float* __restrict__ z, const float* __restrict__ par,
        float* __restrict__ dst) {
    int o0 = lane, o1 = lane + 64;
    bool v0 = o0 < DOUT, v1 = o1 < DOUT;
    int c0 = v0 ? o0 : 0, c1 = v1 ? o1 : 0;
    float d0 = 0.f, d1 = 0.f;
    for (int f = 0; f < DIN; f++) {
        float v = xr[f];
        d0 = fmaf(v, z[f * DOUT + c0], d0);
        if (DOUT > 64) d1 = fmaf(v, z[f * DOUT + c1], d1);
    }
    float denom = fmaxf(1.0f - cx2, EPSF);
    float zn0 = par[c0], ch0 = par[DOUT + c0], sh0 = par[2 * DOUT + c0];
    float arg0 = (2.0f * (d0 / zn0) * ch0 - (1.0f + cx2) * sh0) / denom;
    float y0 = sinh_k_asinh(arg0, 2.0f * zn0);
    float y1 = 0.f;
    if (DOUT > 64) {
        float zn1 = par[c1], ch1 = par[DOUT + c1], sh1 = par[2 * DOUT + c1];
        float arg1 = (2.0f * (d1 / zn1) * ch1 - (1.0f + cx2) * sh1) / denom;
        y1 = sinh_k_asinh(arg1, 2.0f * zn1);
    }
    float ys2 = wave_reduce_sum((v0 ? y0 * y0 : 0.f) + (v1 ? y1 * y1 : 0.f));
    float dnm = 1.0f + sqrtf(1.0f + ys2);
    float ny2 = ys2 / (dnm * dnm);
    float ny = fmaxf(sqrtf(ny2), EPSF);
    float pf = fminf(1.0f, MAXN / ny);
    float sc = pf / dnm;
    if (!RELU) {
        if (v0) dst[o0] = sc * y0;
        if (DOUT > 64 && v1) dst[o1] = sc * y1;
        return pf * pf * ny2;
    }
    float n2b = pf * pf * ny2;
    float nb = fmaxf(sqrtf(n2b), EPSF);
    float fb = fast_atanh01(fminf(nb, 1.0f - 1e-7f)) / nb;
    float u0 = fmaxf(fb * sc * y0, 0.f);
    float u1 = fmaxf(fb * sc * y1, 0.f);
    float m2 = wave_reduce_sum((v0 ? u0 * u0 : 0.f) + (v1 ? u1 * u1 : 0.f));
    float m = fmaxf(sqrtf(m2), EPSF);
    float tm = fast_tanh_pos(m);
    float g = tm / m * fminf(1.0f, MAXN / fmaxf(tm, EPSF));
    if (v0) dst[o0] = g * u0;
    if (DOUT > 64 && v1) dst[o1] = g * u1;
    return g * g * m2;
}

__global__ __launch_bounds__(256) void fc_stack_kernel(const float* __restrict__ in,
        const float* __restrict__ zf1, const float* __restrict__ zf2,
        const float* __restrict__ zf3, const float* __restrict__ ws,
        float* __restrict__ out) {
    __shared__ float xs[4][400];
    __shared__ float h1[4][120];
    __shared__ float h2[4][84];
    int wid = threadIdx.x >> 6, lane = threadIdx.x & 63;
    int b = blockIdx.x * 4 + wid;
    float* xr = xs[wid];
    float p = 0.f;
    for (int j = lane; j < 400; j += 64) { float v = in[(size_t)b * 400 + j]; xr[j] = v; p += v * v; }
    float cx2 = wave_reduce_sum(p);
    __syncthreads();
    float cx2b = fc_layer_wave<400, 120, true >(lane, xr,      cx2,  zf1, ws + OFF_PF1, h1[wid]);
    __syncthreads();
    float cx2c = fc_layer_wave<120, 84,  true >(lane, h1[wid], cx2b, zf2, ws + OFF_PF2, h2[wid]);
    __syncthreads();
    fc_layer_wave<84, 10, false>(lane, h2[wid], cx2c, zf3, ws + OFF_PF3, out + (size_t)b * 10);
}

// ---------------------------------------------------------------------------
static double beta_fn(double n) {
    return exp(lgamma(n / 2.0) + lgamma(0.5) - lgamma((n + 1) / 2.0));
}

extern "C" void kernel_launch(void* const* d_in, const int* in_sizes, int n_in,
                              void* d_out, int out_size, void* d_ws, size_t ws_size,
                              hipStream_t stream) {
    (void)in_sizes; (void)n_in; (void)out_size; (void)ws_size;
    const float* x   = (const float*)d_in[0];
    const float* z1  = (const float*)d_in[1];
    const float* b1  = (const float*)d_in[2];
    const float* z2  = (const float*)d_in[3];
    const float* b2  = (const float*)d_in[4];
    const float* zf1 = (const float*)d_in[5];
    const float* bf1 = (const float*)d_in[6];
    const float* zf2 = (const float*)d_in[7];
    const float* bf2 = (const float*)d_in[8];
    const float* zf3 = (const float*)d_in[9];
    const float* bf3 = (const float*)d_in[10];
    float* out = (float*)d_out;
    float* ws  = (float*)d_ws;

    const float ratio1 = (float)(beta_fn(75.0)  / beta_fn(3.0));
    const float ratio2 = (float)(beta_fn(150.0) / beta_fn(6.0));
    const float ratio3 = (float)(beta_fn(400.0) / beta_fn(6.0) * beta_fn(6.0) / beta_fn(16.0));

    float* buf1 = ws + OFF_BUF1;
    float* buf3 = ws + OFF_BUF3;

    prep_kernel<<<236, 64, 0, stream>>>(z1, b1, z2, b2, zf1, bf1, zf2, bf2, zf3, bf3, ws);
    conv1_kernel<<<512, 256, 0, stream>>>(x, ws, buf1, ratio1);
    conv2_kernel<<<256, 256, 0, stream>>>(buf1, ws, buf3, ratio2, ratio3);
    fc_stack_kernel<<<256, 256, 0, stream>>>(buf3, zf1, zf2, zf3, ws, out);
}